// Round 1
// baseline (125.246 us; speedup 1.0000x reference)
//
#include <hip/hip_runtime.h>
#include <cstdint>
#include <cmath>

#define DENSITY   0.05f
#define TOP_IG    7
#define NT        256
#define FEAT      4096
#define FEAT4     1024
#define PER_T4    4     // float4 per thread in row kernel
#define PER_T     16    // scalars per thread in row kernel

// monotonic float -> uint order key (ascending float == ascending key)
__device__ __forceinline__ unsigned fkey(float f) {
    unsigned u = __float_as_uint(f);
    return (u & 0x80000000u) ? ~u : (u | 0x80000000u);
}
__device__ __forceinline__ float fkey_inv(unsigned k) {
    unsigned u = (k & 0x80000000u) ? (k & 0x7fffffffu) : ~k;
    return __uint_as_float(u);
}

// ---------------- kernel 1: chunked column partial sums ----------------
__global__ __launch_bounds__(NT)
void k_colsum_partial(const float4* __restrict__ x4, float4* __restrict__ part4,
                      int B, int F4v, int rowsPerChunk) {
    int cg = blockIdx.x * NT + threadIdx.x;
    if (cg >= F4v) return;
    int r0 = blockIdx.y * rowsPerChunk;
    int r1 = r0 + rowsPerChunk; if (r1 > B) r1 = B;
    float4 s = make_float4(0.f, 0.f, 0.f, 0.f);
    #pragma unroll 4
    for (int r = r0; r < r1; ++r) {
        float4 v = x4[(size_t)r * F4v + cg];
        s.x += v.x; s.y += v.y; s.z += v.z; s.w += v.w;
    }
    part4[(size_t)blockIdx.y * F4v + cg] = s;
}

// ------------- kernel 2: reduce partials -> mean; compute factor -------------
__global__ __launch_bounds__(NT)
void k_finalize_stats(const float4* __restrict__ part4, const float4* __restrict__ aa4,
                      float4* __restrict__ mean4, float4* __restrict__ factor4,
                      int B, int F4v, int nChunks) {
    __shared__ float4 red[4][64];
    int lane = threadIdx.x & 63;
    int q    = threadIdx.x >> 6;
    int cg   = blockIdx.x * 64 + lane;
    float4 s = make_float4(0.f, 0.f, 0.f, 0.f);
    if (cg < F4v) {
        for (int ch = q; ch < nChunks; ch += 4) {
            float4 v = part4[(size_t)ch * F4v + cg];
            s.x += v.x; s.y += v.y; s.z += v.z; s.w += v.w;
        }
    }
    red[q][lane] = s;
    __syncthreads();
    if (q == 0 && cg < F4v) {
        float4 a0 = red[0][lane], a1 = red[1][lane], a2 = red[2][lane], a3 = red[3][lane];
        float invB = 1.0f / (float)B;
        mean4[cg] = make_float4((a0.x + a1.x + a2.x + a3.x) * invB,
                                (a0.y + a1.y + a2.y + a3.y) * invB,
                                (a0.z + a1.z + a2.z + a3.z) * invB,
                                (a0.w + a1.w + a2.w + a3.w) * invB);
        float4 a = aa4[cg];
        factor4[cg] = make_float4((float)exp((double)(DENSITY - a.x)),
                                  (float)exp((double)(DENSITY - a.y)),
                                  (float)exp((double)(DENSITY - a.z)),
                                  (float)exp((double)(DENSITY - a.w)));
    }
}

// ------------- kernel 3: per-row dual radix-select + apply masks -------------
__global__ __launch_bounds__(NT)
void k_select_apply(const float4* __restrict__ x4, const float4* __restrict__ factor4,
                    const float4* __restrict__ mean4, float4* __restrict__ out4,
                    int rankHi, int rankLo) {
    __shared__ __align__(16) unsigned keys[FEAT];
    __shared__ unsigned hist[4][256];
    __shared__ unsigned s_pref[2];
    __shared__ unsigned s_rr[2];

    const int t    = threadIdx.x;
    const int wid  = t >> 6;
    const int lane = t & 63;
    const size_t rowBase = (size_t)blockIdx.x * FEAT4;

    // ---- load row, build order keys in LDS, keep x in registers ----
    float4 xv[PER_T4];
    #pragma unroll
    for (int j = 0; j < PER_T4; ++j) {
        int v = t + NT * j;
        float4 X  = x4[rowBase + v];
        float4 Fa = factor4[v];
        xv[j] = X;
        *reinterpret_cast<uint4*>(&keys[4 * v]) =
            make_uint4(fkey(X.x * Fa.x), fkey(X.y * Fa.y),
                       fkey(X.z * Fa.z), fkey(X.w * Fa.w));
    }
    if (t == 0) { s_pref[0] = 0u; s_pref[1] = 0u;
                  s_rr[0] = (unsigned)rankHi; s_rr[1] = (unsigned)rankLo; }
    hist[0][t] = 0u; hist[1][t] = 0u; hist[2][t] = 0u; hist[3][t] = 0u;
    __syncthreads();

    // ---- pass 1 (bits 31..24): per-wave private histograms ----
    #pragma unroll
    for (int j = 0; j < PER_T; ++j) {
        unsigned k = keys[t + NT * j];
        atomicAdd(&hist[wid][k >> 24], 1u);
    }
    __syncthreads();

    if (wid == 0) {
        int b0 = lane * 4;
        unsigned c0 = hist[0][b0+0] + hist[1][b0+0] + hist[2][b0+0] + hist[3][b0+0];
        unsigned c1 = hist[0][b0+1] + hist[1][b0+1] + hist[2][b0+1] + hist[3][b0+1];
        unsigned c2 = hist[0][b0+2] + hist[1][b0+2] + hist[2][b0+2] + hist[3][b0+2];
        unsigned c3 = hist[0][b0+3] + hist[1][b0+3] + hist[2][b0+3] + hist[3][b0+3];
        unsigned L = c0 + c1 + c2 + c3;
        unsigned P = L;
        #pragma unroll
        for (int off = 1; off < 64; off <<= 1) {
            unsigned n = __shfl_up(P, off, 64);
            if (lane >= off) P += n;
        }
        unsigned TOT = __shfl(P, 63, 64);
        unsigned SS0 = TOT - P + L;          // suffix-sum (count of keys with digit >= b0)
        unsigned SS1 = SS0 - c0, SS2 = SS1 - c1, SS3 = SS2 - c2, SS4 = SS3 - c3;
        #pragma unroll
        for (int tg = 0; tg < 2; ++tg) {
            unsigned rr = s_rr[tg];
            unsigned pf = s_pref[tg];
            if (SS0 >= rr && SS1 < rr)      { s_pref[tg] = (pf<<8) | (unsigned)(b0+0); s_rr[tg] = rr - SS1; }
            else if (SS1 >= rr && SS2 < rr) { s_pref[tg] = (pf<<8) | (unsigned)(b0+1); s_rr[tg] = rr - SS2; }
            else if (SS2 >= rr && SS3 < rr) { s_pref[tg] = (pf<<8) | (unsigned)(b0+2); s_rr[tg] = rr - SS3; }
            else if (SS3 >= rr && SS4 < rr) { s_pref[tg] = (pf<<8) | (unsigned)(b0+3); s_rr[tg] = rr - SS4; }
        }
    }
    __syncthreads();

    // ---- passes 2..4: restricted to current prefixes, dual target ----
    #pragma unroll
    for (int pass = 1; pass < 4; ++pass) {
        const int shift = 24 - 8 * pass;
        hist[0][t] = 0u; hist[1][t] = 0u;
        __syncthreads();
        const unsigned pref0 = s_pref[0], pref1 = s_pref[1];
        #pragma unroll
        for (int j = 0; j < PER_T; ++j) {
            unsigned k  = keys[t + NT * j];
            unsigned hi = k >> (shift + 8);
            if (hi == pref0) atomicAdd(&hist[0][(k >> shift) & 255u], 1u);
            if (hi == pref1) atomicAdd(&hist[1][(k >> shift) & 255u], 1u);
        }
        __syncthreads();
        if (wid == 0) {
            #pragma unroll
            for (int tg = 0; tg < 2; ++tg) {
                int b0 = lane * 4;
                unsigned c0 = hist[tg][b0+0], c1 = hist[tg][b0+1];
                unsigned c2 = hist[tg][b0+2], c3 = hist[tg][b0+3];
                unsigned L = c0 + c1 + c2 + c3;
                unsigned P = L;
                #pragma unroll
                for (int off = 1; off < 64; off <<= 1) {
                    unsigned n = __shfl_up(P, off, 64);
                    if (lane >= off) P += n;
                }
                unsigned TOT = __shfl(P, 63, 64);
                unsigned SS0 = TOT - P + L;
                unsigned SS1 = SS0 - c0, SS2 = SS1 - c1, SS3 = SS2 - c2, SS4 = SS3 - c3;
                unsigned rr = s_rr[tg];
                unsigned pf = s_pref[tg];
                if (SS0 >= rr && SS1 < rr)      { s_pref[tg] = (pf<<8) | (unsigned)(b0+0); s_rr[tg] = rr - SS1; }
                else if (SS1 >= rr && SS2 < rr) { s_pref[tg] = (pf<<8) | (unsigned)(b0+1); s_rr[tg] = rr - SS2; }
                else if (SS2 >= rr && SS3 < rr) { s_pref[tg] = (pf<<8) | (unsigned)(b0+2); s_rr[tg] = rr - SS3; }
                else if (SS3 >= rr && SS4 < rr) { s_pref[tg] = (pf<<8) | (unsigned)(b0+3); s_rr[tg] = rr - SS4; }
            }
        }
        __syncthreads();
    }

    // ---- apply masks: exact float thresholds recovered from keys ----
    const float hiT = fkey_inv(s_pref[0]);   // top_ig (rank 7)
    const float loT = fkey_inv(s_pref[1]);   // kth    (rank 211)

    #pragma unroll
    for (int j = 0; j < PER_T4; ++j) {
        int v = t + NT * j;
        uint4 kk = *reinterpret_cast<const uint4*>(&keys[4 * v]);
        float4 X = xv[j];
        float4 M = mean4[v];
        float xp0 = fkey_inv(kk.x), xp1 = fkey_inv(kk.y);
        float xp2 = fkey_inv(kk.z), xp3 = fkey_inv(kk.w);
        float4 o;
        o.x = (xp0 <= hiT) ? ((xp0 >= loT) ? X.x - M.x : -M.x) : 0.0f;
        o.y = (xp1 <= hiT) ? ((xp1 >= loT) ? X.y - M.y : -M.y) : 0.0f;
        o.z = (xp2 <= hiT) ? ((xp2 >= loT) ? X.z - M.z : -M.z) : 0.0f;
        o.w = (xp3 <= hiT) ? ((xp3 >= loT) ? X.w - M.w : -M.w) : 0.0f;
        out4[rowBase + v] = o;
    }
}

extern "C" void kernel_launch(void* const* d_in, const int* in_sizes, int n_in,
                              void* d_out, int out_size, void* d_ws, size_t ws_size,
                              hipStream_t stream) {
    const float* x  = (const float*)d_in[0];
    const float* aa = (const float*)d_in[1];
    float* out = (float*)d_out;

    const int F   = in_sizes[1];          // 4096
    const int B   = in_sizes[0] / F;      // 8192
    const int F4v = F / 4;
    const int rankLo = (int)((double)F * 0.05) + TOP_IG;   // 211
    const int rankHi = TOP_IG;                              // 7

    int nChunks = 256;
    while (nChunks > 1 &&
           ((size_t)nChunks + 2) * (size_t)F * sizeof(float) > ws_size)
        nChunks >>= 1;

    float* part   = (float*)d_ws;
    float* mean   = part + (size_t)nChunks * F;
    float* factor = mean + F;
    int rpc = (B + nChunks - 1) / nChunks;

    dim3 g1((F4v + NT - 1) / NT, nChunks);
    k_colsum_partial<<<g1, NT, 0, stream>>>((const float4*)x, (float4*)part, B, F4v, rpc);

    k_finalize_stats<<<dim3((F4v + 63) / 64), NT, 0, stream>>>(
        (const float4*)part, (const float4*)aa, (float4*)mean, (float4*)factor, B, F4v, nChunks);

    k_select_apply<<<dim3(B), NT, 0, stream>>>(
        (const float4*)x, (const float4*)factor, (const float4*)mean, (float4*)out,
        rankHi, rankLo);
}

// Round 2
// 122.679 us; speedup vs baseline: 1.0209x; 1.0209x over previous
//
#include <hip/hip_runtime.h>
#include <cstdint>
#include <cmath>

#define DENSITY   0.05f
#define TOP_IG    7
#define NT        256
#define NT1       64
#define FEAT      4096
#define FEAT4     1024
#define PER_T4    4     // float4 per thread in row kernel
#define PER_T     16    // scalars per thread in row kernel

// monotonic float -> uint order key (ascending float == ascending key)
__device__ __forceinline__ unsigned fkey(float f) {
    unsigned u = __float_as_uint(f);
    return (u & 0x80000000u) ? ~u : (u | 0x80000000u);
}

// ---------------- kernel 1: chunked column partial sums ----------------
__global__ __launch_bounds__(NT1)
void k_colsum_partial(const float4* __restrict__ x4, float4* __restrict__ part4,
                      int B, int F4v, int rowsPerChunk) {
    int cg = blockIdx.x * NT1 + threadIdx.x;
    if (cg >= F4v) return;
    int r0 = blockIdx.y * rowsPerChunk;
    int r1 = r0 + rowsPerChunk; if (r1 > B) r1 = B;
    float4 s0 = make_float4(0.f,0.f,0.f,0.f), s1 = s0, s2 = s0, s3 = s0;
    int r = r0;
    for (; r + 4 <= r1; r += 4) {
        float4 a = x4[(size_t)(r+0) * F4v + cg];
        float4 b = x4[(size_t)(r+1) * F4v + cg];
        float4 c = x4[(size_t)(r+2) * F4v + cg];
        float4 d = x4[(size_t)(r+3) * F4v + cg];
        s0.x += a.x; s0.y += a.y; s0.z += a.z; s0.w += a.w;
        s1.x += b.x; s1.y += b.y; s1.z += b.z; s1.w += b.w;
        s2.x += c.x; s2.y += c.y; s2.z += c.z; s2.w += c.w;
        s3.x += d.x; s3.y += d.y; s3.z += d.z; s3.w += d.w;
    }
    for (; r < r1; ++r) {
        float4 a = x4[(size_t)r * F4v + cg];
        s0.x += a.x; s0.y += a.y; s0.z += a.z; s0.w += a.w;
    }
    float4 s = make_float4(s0.x+s1.x+s2.x+s3.x, s0.y+s1.y+s2.y+s3.y,
                           s0.z+s1.z+s2.z+s3.z, s0.w+s1.w+s2.w+s3.w);
    part4[(size_t)blockIdx.y * F4v + cg] = s;
}

// ------------- kernel 2: reduce partials -> mean; compute factor -------------
__global__ __launch_bounds__(NT)
void k_finalize_stats(const float4* __restrict__ part4, const float4* __restrict__ aa4,
                      float4* __restrict__ mean4, float4* __restrict__ factor4,
                      int B, int F4v, int nChunks) {
    __shared__ float4 red[4][64];
    int lane = threadIdx.x & 63;
    int q    = threadIdx.x >> 6;
    int cg   = blockIdx.x * 64 + lane;
    float4 s = make_float4(0.f, 0.f, 0.f, 0.f);
    if (cg < F4v) {
        for (int ch = q; ch < nChunks; ch += 4) {
            float4 v = part4[(size_t)ch * F4v + cg];
            s.x += v.x; s.y += v.y; s.z += v.z; s.w += v.w;
        }
    }
    red[q][lane] = s;
    __syncthreads();
    if (q == 0 && cg < F4v) {
        float4 a0 = red[0][lane], a1 = red[1][lane], a2 = red[2][lane], a3 = red[3][lane];
        float invB = 1.0f / (float)B;
        mean4[cg] = make_float4((a0.x + a1.x + a2.x + a3.x) * invB,
                                (a0.y + a1.y + a2.y + a3.y) * invB,
                                (a0.z + a1.z + a2.z + a3.z) * invB,
                                (a0.w + a1.w + a2.w + a3.w) * invB);
        float4 a = aa4[cg];
        factor4[cg] = make_float4((float)exp((double)(DENSITY - a.x)),
                                  (float)exp((double)(DENSITY - a.y)),
                                  (float)exp((double)(DENSITY - a.z)),
                                  (float)exp((double)(DENSITY - a.w)));
    }
}

// one radix step: counts c0..c3 for this lane's 4 bins -> update (pref, rr)
__device__ __forceinline__ void radix_step(unsigned c0, unsigned c1, unsigned c2, unsigned c3,
                                           int lane, unsigned& pref, unsigned& rr) {
    unsigned L = c0 + c1 + c2 + c3;
    unsigned P = L;
    #pragma unroll
    for (int off = 1; off < 64; off <<= 1) {
        unsigned n = __shfl_up(P, off, 64);
        if (lane >= off) P += n;
    }
    unsigned TOT = __shfl(P, 63, 64);
    unsigned SS0 = TOT - P + L;               // suffix sums: #keys with digit >= bin
    unsigned SS1 = SS0 - c0, SS2 = SS1 - c1, SS3 = SS2 - c2, SS4 = SS3 - c3;
    unsigned pack = 0; bool m = false;
    unsigned b0 = (unsigned)(lane << 2);
    if      (SS0 >= rr && SS1 < rr) { pack = ((b0+0u) << 16) | (rr - SS1); m = true; }
    else if (SS1 >= rr && SS2 < rr) { pack = ((b0+1u) << 16) | (rr - SS2); m = true; }
    else if (SS2 >= rr && SS3 < rr) { pack = ((b0+2u) << 16) | (rr - SS3); m = true; }
    else if (SS3 >= rr && SS4 < rr) { pack = ((b0+3u) << 16) | (rr - SS4); m = true; }
    unsigned long long mk = __ballot(m);
    int src = __ffsll((unsigned long long)mk) - 1;
    pack = __shfl(pack, src, 64);
    pref = (pref << 8) | (pack >> 16);
    rr   = pack & 0xffffu;
}

// ------------- kernel 3: per-row dual radix-select + apply masks -------------
// keys stay in registers; LDS holds histograms only.
__global__ __launch_bounds__(NT)
void k_select_apply(const float4* __restrict__ x4, const float4* __restrict__ factor4,
                    const float4* __restrict__ mean4, float4* __restrict__ out4,
                    int rankHi, int rankLo) {
    __shared__ unsigned hist1[4][256];      // pass 1: per-wave private
    __shared__ unsigned hist2[3][2][256];   // passes 2..4: [buf][target][bin], pre-zeroed

    const int t    = threadIdx.x;
    const int wid  = t >> 6;
    const int lane = t & 63;
    const size_t rowBase = (size_t)blockIdx.x * FEAT4;

    // ---- init: zero histograms ----
    hist1[0][t] = 0u; hist1[1][t] = 0u; hist1[2][t] = 0u; hist1[3][t] = 0u;
    #pragma unroll
    for (int b = 0; b < 3; ++b) { hist2[b][0][t] = 0u; hist2[b][1][t] = 0u; }

    // ---- load row, build order keys in registers ----
    float4   xv[PER_T4];
    unsigned kk[PER_T];
    #pragma unroll
    for (int j = 0; j < PER_T4; ++j) {
        int v = t + NT * j;
        float4 X  = x4[rowBase + v];
        float4 Fa = factor4[v];
        xv[j] = X;
        kk[4*j+0] = fkey(X.x * Fa.x);
        kk[4*j+1] = fkey(X.y * Fa.y);
        kk[4*j+2] = fkey(X.z * Fa.z);
        kk[4*j+3] = fkey(X.w * Fa.w);
    }
    __syncthreads();   // hist zeroed

    unsigned pref0 = 0u, rr0 = (unsigned)rankHi;
    unsigned pref1 = 0u, rr1 = (unsigned)rankLo;

    // ---- pass 1 (bits 31..24): per-wave private histograms ----
    #pragma unroll
    for (int j = 0; j < PER_T; ++j)
        atomicAdd(&hist1[wid][kk[j] >> 24], 1u);
    __syncthreads();

    {   // merge 4 wave-hists, scan, select — redundantly on every wave
        uint4 h0 = *reinterpret_cast<const uint4*>(&hist1[0][lane << 2]);
        uint4 h1 = *reinterpret_cast<const uint4*>(&hist1[1][lane << 2]);
        uint4 h2 = *reinterpret_cast<const uint4*>(&hist1[2][lane << 2]);
        uint4 h3 = *reinterpret_cast<const uint4*>(&hist1[3][lane << 2]);
        unsigned c0 = h0.x + h1.x + h2.x + h3.x;
        unsigned c1 = h0.y + h1.y + h2.y + h3.y;
        unsigned c2 = h0.z + h1.z + h2.z + h3.z;
        unsigned c3 = h0.w + h1.w + h2.w + h3.w;
        radix_step(c0, c1, c2, c3, lane, pref0, rr0);
        radix_step(c0, c1, c2, c3, lane, pref1, rr1);
    }
    // no barrier: next pass writes hist2[0], disjoint from hist1

    // ---- passes 2..4: prefix-filtered, dual-target, triple-buffered ----
    #pragma unroll
    for (int pass = 0; pass < 3; ++pass) {
        const int shift = 16 - 8 * pass;
        #pragma unroll
        for (int j = 0; j < PER_T; ++j) {
            unsigned k  = kk[j];
            unsigned hi = k >> (shift + 8);
            unsigned d  = (k >> shift) & 255u;
            if (hi == pref0) atomicAdd(&hist2[pass][0][d], 1u);
            if (hi == pref1) atomicAdd(&hist2[pass][1][d], 1u);
        }
        __syncthreads();
        uint4 g0 = *reinterpret_cast<const uint4*>(&hist2[pass][0][lane << 2]);
        uint4 g1 = *reinterpret_cast<const uint4*>(&hist2[pass][1][lane << 2]);
        radix_step(g0.x, g0.y, g0.z, g0.w, lane, pref0, rr0);
        radix_step(g1.x, g1.y, g1.z, g1.w, lane, pref1, rr1);
        // no barrier: next pass uses a fresh pre-zeroed buffer
    }

    // ---- apply masks: pref0/pref1 are the exact 32-bit keys of ranks 7/211 ----
    const unsigned keyHi = pref0;   // fkey(top_ig)
    const unsigned keyLo = pref1;   // fkey(kth)

    #pragma unroll
    for (int j = 0; j < PER_T4; ++j) {
        int v = t + NT * j;
        float4 X = xv[j];
        float4 M = mean4[v];
        unsigned k0 = kk[4*j+0], k1 = kk[4*j+1], k2 = kk[4*j+2], k3 = kk[4*j+3];
        float4 o;
        o.x = (k0 <= keyHi) ? ((k0 >= keyLo) ? X.x - M.x : -M.x) : 0.0f;
        o.y = (k1 <= keyHi) ? ((k1 >= keyLo) ? X.y - M.y : -M.y) : 0.0f;
        o.z = (k2 <= keyHi) ? ((k2 >= keyLo) ? X.z - M.z : -M.z) : 0.0f;
        o.w = (k3 <= keyHi) ? ((k3 >= keyLo) ? X.w - M.w : -M.w) : 0.0f;
        out4[rowBase + v] = o;
    }
}

extern "C" void kernel_launch(void* const* d_in, const int* in_sizes, int n_in,
                              void* d_out, int out_size, void* d_ws, size_t ws_size,
                              hipStream_t stream) {
    const float* x  = (const float*)d_in[0];
    const float* aa = (const float*)d_in[1];
    float* out = (float*)d_out;

    const int F   = in_sizes[1];          // 4096
    const int B   = in_sizes[0] / F;      // 8192
    const int F4v = F / 4;
    const int rankLo = (int)((double)F * 0.05) + TOP_IG;   // 211
    const int rankHi = TOP_IG;                              // 7

    int nChunks = 256;
    while (nChunks > 1 &&
           ((size_t)nChunks + 2) * (size_t)F * sizeof(float) > ws_size)
        nChunks >>= 1;

    float* part   = (float*)d_ws;
    float* mean   = part + (size_t)nChunks * F;
    float* factor = mean + F;
    int rpc = (B + nChunks - 1) / nChunks;

    dim3 g1((F4v + NT1 - 1) / NT1, nChunks);
    k_colsum_partial<<<g1, NT1, 0, stream>>>((const float4*)x, (float4*)part, B, F4v, rpc);

    k_finalize_stats<<<dim3((F4v + 63) / 64), NT, 0, stream>>>(
        (const float4*)part, (const float4*)aa, (float4*)mean, (float4*)factor, B, F4v, nChunks);

    k_select_apply<<<dim3(B), NT, 0, stream>>>(
        (const float4*)x, (const float4*)factor, (const float4*)mean, (float4*)out,
        rankHi, rankLo);
}

// Round 3
// 121.276 us; speedup vs baseline: 1.0327x; 1.0116x over previous
//
#include <hip/hip_runtime.h>
#include <cstdint>
#include <cmath>

#define DENSITY   0.05f
#define TOP_IG    7
#define NT        256
#define NT1       64
#define FEAT      4096
#define FEAT4     1024
#define PER_T4    4     // float4 per thread in row kernel
#define PER_T     16    // scalars per thread in row kernel
#define NREP      8     // pass-1 histogram replicas
#define RSTRIDE   257   // odd stride: replica r's bin b lands in bank (b + r) % 32

// monotonic float -> uint order key (ascending float == ascending key)
__device__ __forceinline__ unsigned fkey(float f) {
    unsigned u = __float_as_uint(f);
    return (u & 0x80000000u) ? ~u : (u | 0x80000000u);
}

// ---------------- kernel 1: chunked column partial sums ----------------
__global__ __launch_bounds__(NT1)
void k_colsum_partial(const float4* __restrict__ x4, float4* __restrict__ part4,
                      int B, int F4v, int rowsPerChunk) {
    int cg = blockIdx.x * NT1 + threadIdx.x;
    if (cg >= F4v) return;
    int r0 = blockIdx.y * rowsPerChunk;
    int r1 = r0 + rowsPerChunk; if (r1 > B) r1 = B;
    float4 s0 = make_float4(0.f,0.f,0.f,0.f), s1 = s0, s2 = s0, s3 = s0;
    int r = r0;
    for (; r + 4 <= r1; r += 4) {
        float4 a = x4[(size_t)(r+0) * F4v + cg];
        float4 b = x4[(size_t)(r+1) * F4v + cg];
        float4 c = x4[(size_t)(r+2) * F4v + cg];
        float4 d = x4[(size_t)(r+3) * F4v + cg];
        s0.x += a.x; s0.y += a.y; s0.z += a.z; s0.w += a.w;
        s1.x += b.x; s1.y += b.y; s1.z += b.z; s1.w += b.w;
        s2.x += c.x; s2.y += c.y; s2.z += c.z; s2.w += c.w;
        s3.x += d.x; s3.y += d.y; s3.z += d.z; s3.w += d.w;
    }
    for (; r < r1; ++r) {
        float4 a = x4[(size_t)r * F4v + cg];
        s0.x += a.x; s0.y += a.y; s0.z += a.z; s0.w += a.w;
    }
    float4 s = make_float4(s0.x+s1.x+s2.x+s3.x, s0.y+s1.y+s2.y+s3.y,
                           s0.z+s1.z+s2.z+s3.z, s0.w+s1.w+s2.w+s3.w);
    part4[(size_t)blockIdx.y * F4v + cg] = s;
}

// ------------- kernel 2: reduce partials -> mean; compute factor -------------
__global__ __launch_bounds__(NT)
void k_finalize_stats(const float4* __restrict__ part4, const float4* __restrict__ aa4,
                      float4* __restrict__ mean4, float4* __restrict__ factor4,
                      int B, int F4v, int nChunks) {
    __shared__ float4 red[4][64];
    int lane = threadIdx.x & 63;
    int q    = threadIdx.x >> 6;
    int cg   = blockIdx.x * 64 + lane;
    float4 s = make_float4(0.f, 0.f, 0.f, 0.f);
    if (cg < F4v) {
        for (int ch = q; ch < nChunks; ch += 4) {
            float4 v = part4[(size_t)ch * F4v + cg];
            s.x += v.x; s.y += v.y; s.z += v.z; s.w += v.w;
        }
    }
    red[q][lane] = s;
    __syncthreads();
    if (q == 0 && cg < F4v) {
        float4 a0 = red[0][lane], a1 = red[1][lane], a2 = red[2][lane], a3 = red[3][lane];
        float invB = 1.0f / (float)B;
        mean4[cg] = make_float4((a0.x + a1.x + a2.x + a3.x) * invB,
                                (a0.y + a1.y + a2.y + a3.y) * invB,
                                (a0.z + a1.z + a2.z + a3.z) * invB,
                                (a0.w + a1.w + a2.w + a3.w) * invB);
        float4 a = aa4[cg];
        factor4[cg] = make_float4((float)exp((double)(DENSITY - a.x)),
                                  (float)exp((double)(DENSITY - a.y)),
                                  (float)exp((double)(DENSITY - a.z)),
                                  (float)exp((double)(DENSITY - a.w)));
    }
}

// one radix step: counts c0..c3 for this lane's 4 bins -> update (pref, rr)
__device__ __forceinline__ void radix_step(unsigned c0, unsigned c1, unsigned c2, unsigned c3,
                                           int lane, unsigned& pref, unsigned& rr) {
    unsigned L = c0 + c1 + c2 + c3;
    unsigned P = L;
    #pragma unroll
    for (int off = 1; off < 64; off <<= 1) {
        unsigned n = __shfl_up(P, off, 64);
        if (lane >= off) P += n;
    }
    unsigned TOT = __shfl(P, 63, 64);
    unsigned SS0 = TOT - P + L;               // suffix sums: #keys with digit >= bin
    unsigned SS1 = SS0 - c0, SS2 = SS1 - c1, SS3 = SS2 - c2, SS4 = SS3 - c3;
    unsigned pack = 0; bool m = false;
    unsigned b0 = (unsigned)(lane << 2);
    if      (SS0 >= rr && SS1 < rr) { pack = ((b0+0u) << 16) | (rr - SS1); m = true; }
    else if (SS1 >= rr && SS2 < rr) { pack = ((b0+1u) << 16) | (rr - SS2); m = true; }
    else if (SS2 >= rr && SS3 < rr) { pack = ((b0+2u) << 16) | (rr - SS3); m = true; }
    else if (SS3 >= rr && SS4 < rr) { pack = ((b0+3u) << 16) | (rr - SS4); m = true; }
    unsigned long long mk = __ballot(m);
    int src = __ffsll((unsigned long long)mk) - 1;
    pack = __shfl(pack, src, 64);
    pref = (pref << 8) | (pack >> 16);
    rr   = pack & 0xffffu;
}

// ------------- kernel 3: per-row dual radix-select + apply masks -------------
// keys in registers; pass-1 histogram is replicated + bank-staggered to kill
// same-address atomic serialization on the concentrated exponent bins.
__global__ __launch_bounds__(NT)
void k_select_apply(const float4* __restrict__ x4, const float4* __restrict__ factor4,
                    const float4* __restrict__ mean4, float4* __restrict__ out4,
                    int rankHi, int rankLo) {
    __shared__ unsigned hist1[NREP * RSTRIDE];            // pass 1 replicas (8.2 KB)
    __shared__ __align__(16) unsigned merged[256];        // merged pass-1 histogram
    __shared__ unsigned hist2[3][2][256];                 // passes 2..4, pre-zeroed

    const int t    = threadIdx.x;
    const int lane = t & 63;
    const size_t rowBase = (size_t)blockIdx.x * FEAT4;

    // ---- init: zero histograms ----
    #pragma unroll
    for (int i = t; i < NREP * RSTRIDE; i += NT) hist1[i] = 0u;
    #pragma unroll
    for (int b = 0; b < 3; ++b) { hist2[b][0][t] = 0u; hist2[b][1][t] = 0u; }

    // ---- load row + mean, build order keys in registers ----
    float4   xv[PER_T4];
    float4   mv[PER_T4];
    unsigned kk[PER_T];
    #pragma unroll
    for (int j = 0; j < PER_T4; ++j) {
        int v = t + NT * j;
        float4 X  = x4[rowBase + v];
        float4 Fa = factor4[v];
        mv[j] = mean4[v];                 // prefetch early; consumed only at the end
        xv[j] = X;
        kk[4*j+0] = fkey(X.x * Fa.x);
        kk[4*j+1] = fkey(X.y * Fa.y);
        kk[4*j+2] = fkey(X.z * Fa.z);
        kk[4*j+3] = fkey(X.w * Fa.w);
    }
    __syncthreads();   // B1: hist zeroed

    unsigned pref0 = 0u, rr0 = (unsigned)rankHi;
    unsigned pref1 = 0u, rr1 = (unsigned)rankLo;

    // ---- pass 1 (bits 31..24): replicated histogram, replica = lane>>3 ----
    {
        unsigned* h1 = &hist1[(unsigned)(lane >> 3) * RSTRIDE];
        #pragma unroll
        for (int j = 0; j < PER_T; ++j)
            atomicAdd(&h1[kk[j] >> 24], 1u);
    }
    __syncthreads();   // B2: atomics done

    // ---- merge replicas cooperatively: merged[t] = sum_r hist1[r][t] ----
    {
        unsigned m = 0;
        #pragma unroll
        for (int r = 0; r < NREP; ++r) m += hist1[r * RSTRIDE + t];
        merged[t] = m;
    }
    __syncthreads();   // B3: merged ready

    {   // scan + select — redundantly on every wave (no idle waves, no LDS round-trip)
        uint4 c = *reinterpret_cast<const uint4*>(&merged[lane << 2]);
        radix_step(c.x, c.y, c.z, c.w, lane, pref0, rr0);
        radix_step(c.x, c.y, c.z, c.w, lane, pref1, rr1);
    }
    // no barrier: next pass writes hist2[0], disjoint from hist1/merged

    // ---- passes 2..4: prefix-filtered, dual-target, triple-buffered ----
    #pragma unroll
    for (int pass = 0; pass < 3; ++pass) {
        const int shift = 16 - 8 * pass;
        #pragma unroll
        for (int j = 0; j < PER_T; ++j) {
            unsigned k  = kk[j];
            unsigned hi = k >> (shift + 8);
            unsigned d  = (k >> shift) & 255u;
            if (hi == pref0) atomicAdd(&hist2[pass][0][d], 1u);
            if (hi == pref1) atomicAdd(&hist2[pass][1][d], 1u);
        }
        __syncthreads();
        uint4 g0 = *reinterpret_cast<const uint4*>(&hist2[pass][0][lane << 2]);
        uint4 g1 = *reinterpret_cast<const uint4*>(&hist2[pass][1][lane << 2]);
        radix_step(g0.x, g0.y, g0.z, g0.w, lane, pref0, rr0);
        radix_step(g1.x, g1.y, g1.z, g1.w, lane, pref1, rr1);
        // no barrier: next pass uses a fresh pre-zeroed buffer
    }

    // ---- apply masks: pref0/pref1 are the exact 32-bit keys of ranks 7/211 ----
    const unsigned keyHi = pref0;   // fkey(top_ig)
    const unsigned keyLo = pref1;   // fkey(kth)

    #pragma unroll
    for (int j = 0; j < PER_T4; ++j) {
        int v = t + NT * j;
        float4 X = xv[j];
        float4 M = mv[j];
        unsigned k0 = kk[4*j+0], k1 = kk[4*j+1], k2 = kk[4*j+2], k3 = kk[4*j+3];
        float4 o;
        o.x = (k0 <= keyHi) ? ((k0 >= keyLo) ? X.x - M.x : -M.x) : 0.0f;
        o.y = (k1 <= keyHi) ? ((k1 >= keyLo) ? X.y - M.y : -M.y) : 0.0f;
        o.z = (k2 <= keyHi) ? ((k2 >= keyLo) ? X.z - M.z : -M.z) : 0.0f;
        o.w = (k3 <= keyHi) ? ((k3 >= keyLo) ? X.w - M.w : -M.w) : 0.0f;
        out4[rowBase + v] = o;
    }
}

extern "C" void kernel_launch(void* const* d_in, const int* in_sizes, int n_in,
                              void* d_out, int out_size, void* d_ws, size_t ws_size,
                              hipStream_t stream) {
    const float* x  = (const float*)d_in[0];
    const float* aa = (const float*)d_in[1];
    float* out = (float*)d_out;

    const int F   = in_sizes[1];          // 4096
    const int B   = in_sizes[0] / F;      // 8192
    const int F4v = F / 4;
    const int rankLo = (int)((double)F * 0.05) + TOP_IG;   // 211
    const int rankHi = TOP_IG;                              // 7

    int nChunks = 256;
    while (nChunks > 1 &&
           ((size_t)nChunks + 2) * (size_t)F * sizeof(float) > ws_size)
        nChunks >>= 1;

    float* part   = (float*)d_ws;
    float* mean   = part + (size_t)nChunks * F;
    float* factor = mean + F;
    int rpc = (B + nChunks - 1) / nChunks;

    dim3 g1((F4v + NT1 - 1) / NT1, nChunks);
    k_colsum_partial<<<g1, NT1, 0, stream>>>((const float4*)x, (float4*)part, B, F4v, rpc);

    k_finalize_stats<<<dim3((F4v + 63) / 64), NT, 0, stream>>>(
        (const float4*)part, (const float4*)aa, (float4*)mean, (float4*)factor, B, F4v, nChunks);

    k_select_apply<<<dim3(B), NT, 0, stream>>>(
        (const float4*)x, (const float4*)factor, (const float4*)mean, (float4*)out,
        rankHi, rankLo);
}